// Round 1
// baseline (1741.882 us; speedup 1.0000x reference)
//
#include <hip/hip_runtime.h>

#define NN 100000
#define NE 1600000
#define NBUCK 782   // ceil(NN/128), bucket = node >> 7
#define PCHUNK 4096 // edges per k_pairs block -> 391 blocks
#define HISTB 256   // k_hist grid
#define NREP 8      // replicated bucket-count copies

struct alignas(8) US4 { unsigned short x, y, z, w; };

__device__ __forceinline__ float bfu(unsigned int hw) { return __uint_as_float(hw << 16); }
__device__ __forceinline__ unsigned short f2bf(float f) {
    unsigned int u = __float_as_uint(f);
    return (unsigned short)((u + 0x7fffu + ((u >> 16) & 1u)) >> 16);
}

// ---------------- build: dual bucket-ordered edge arrays ----------------

// LDS-only dual histogram (dst buckets + src buckets), replicated global merge.
__global__ __launch_bounds__(256) void k_hist(const int* __restrict__ src,
                                              const int* __restrict__ dst,
                                              int* __restrict__ bcnt8_d,
                                              int* __restrict__ bcnt8_s) {
    __shared__ int hd[NBUCK], hs[NBUCK];
    int tid = threadIdx.x;
    for (int i = tid; i < NBUCK; i += 256) { hd[i] = 0; hs[i] = 0; }
    __syncthreads();
    int* md = bcnt8_d + (size_t)(blockIdx.x & (NREP - 1)) * NBUCK;
    int* ms = bcnt8_s + (size_t)(blockIdx.x & (NREP - 1)) * NBUCK;
    int stride = gridDim.x * 256;
    for (int e = blockIdx.x * 256 + tid; e < NE; e += stride) {
        atomicAdd(&hd[dst[e] >> 7], 1);
        atomicAdd(&hs[src[e] >> 7], 1);
    }
    __syncthreads();
    for (int i = tid; i < NBUCK; i += 256) {
        if (hd[i]) atomicAdd(&md[i], hd[i]);
        if (hs[i]) atomicAdd(&ms[i], hs[i]);
    }
}

// block 0: scan dst buckets; block 1: scan src buckets
__global__ __launch_bounds__(1024) void k_bscan(const int* __restrict__ bcnt8_d,
                                                const int* __restrict__ bcnt8_s,
                                                int* __restrict__ base_d,
                                                int* __restrict__ cursor_d,
                                                int* __restrict__ base_s,
                                                int* __restrict__ cursor_s) {
    __shared__ int tmp[1024];
    int t = threadIdx.x;
    const int* bc = blockIdx.x ? bcnt8_s : bcnt8_d;
    int* base = blockIdx.x ? base_s : base_d;
    int* cur = blockIdx.x ? cursor_s : cursor_d;
    int v = 0;
    if (t < NBUCK)
#pragma unroll
        for (int c = 0; c < NREP; ++c) v += bc[c * NBUCK + t];
    tmp[t] = v;
    __syncthreads();
    for (int off = 1; off < 1024; off <<= 1) {
        int u = (t >= off) ? tmp[t - off] : 0;
        __syncthreads();
        tmp[t] += u;
        __syncthreads();
    }
    int excl = tmp[t] - v;
    if (t < NBUCK) {
        base[t] = excl;
        cur[t] = excl;
    }
    if (t == 0) base[NBUCK] = NE;
}

// dual LDS-binned scatter: bulk reservation per (block,bucket), packed words
// into per-block contiguous runs.  E2d = (src<<7)|(dst&127); E2s = src&127 (byte).
__global__ __launch_bounds__(256) void k_pairs(const int* __restrict__ src,
                                               const int* __restrict__ dst,
                                               int* __restrict__ cursor_d,
                                               int* __restrict__ cursor_s,
                                               int* __restrict__ E2d,
                                               unsigned char* __restrict__ E2s) {
    __shared__ int hist_d[NBUCK], gbase_d[NBUCK], hist_s[NBUCK], gbase_s[NBUCK];
    int tid = threadIdx.x;
    for (int i = tid; i < NBUCK; i += 256) { hist_d[i] = 0; hist_s[i] = 0; }
    __syncthreads();
    int base = blockIdx.x * PCHUNK;
#pragma unroll
    for (int i = 0; i < PCHUNK / 256; ++i) {
        int e = base + i * 256 + tid;
        if (e < NE) {
            atomicAdd(&hist_d[dst[e] >> 7], 1);
            atomicAdd(&hist_s[src[e] >> 7], 1);
        }
    }
    __syncthreads();
    // rotate reservation start per block to decorrelate cursor-line contention
    int rot = (int)((blockIdx.x * 191u) % NBUCK);
    for (int ii = tid; ii < NBUCK; ii += 256) {
        int i = ii + rot;
        if (i >= NBUCK) i -= NBUCK;
        int h = hist_d[i];
        if (h) gbase_d[i] = atomicAdd(&cursor_d[i], h);
        hist_d[i] = 0;
        h = hist_s[i];
        if (h) gbase_s[i] = atomicAdd(&cursor_s[i], h);
        hist_s[i] = 0;
    }
    __syncthreads();
#pragma unroll
    for (int i = 0; i < PCHUNK / 256; ++i) {
        int e = base + i * 256 + tid;
        if (e < NE) {
            int s = src[e], d = dst[e];
            int bd = d >> 7;
            int pd = atomicAdd(&hist_d[bd], 1);
            E2d[gbase_d[bd] + pd] = (s << 7) | (d & 127);
            int bs = s >> 7;
            int ps = atomicAdd(&hist_s[bs], 1);
            E2s[gbase_s[bs] + ps] = (unsigned char)(s & 127);
        }
    }
}

// out-degree only (src buckets): r_out = rsqrt(max(deg_out,1))
__global__ __launch_bounds__(256) void k_out(const unsigned char* __restrict__ E2s,
                                             const int* __restrict__ base_s,
                                             float* __restrict__ r_out) {
    __shared__ int cnt[128];
    int tid = threadIdx.x;
    int b = blockIdx.x;
    int base = base_s[b], end = base_s[b + 1];
    if (tid < 128) cnt[tid] = 0;
    __syncthreads();
    for (int i = base + tid; i < end; i += 256) atomicAdd(&cnt[E2s[i]], 1);
    __syncthreads();
    if (tid < 128) {
        int node = b * 128 + tid;
        if (node < NN) r_out[node] = rsqrtf((float)max(cnt[tid], 1));
    }
}

// ---------------- dense GEMMs ----------------

// A(bf16) = (x @ W0) * r_out.  64 nodes/block, thread = 4m x 4n, K=128 in two halves.
__global__ __launch_bounds__(256) void k_gemm0(const float* __restrict__ x,
                                               const float* __restrict__ W0,
                                               const float* __restrict__ r_out,
                                               unsigned short* __restrict__ A) {
    __shared__ float xl[64 * 129];
    __shared__ float wl[64 * 64];
    int tid = threadIdx.x;
    int m0 = blockIdx.x * 64;
#pragma unroll
    for (int i = 0; i < 8; ++i) {
        int idx = i * 256 + tid;
        int m = idx >> 5, kc = idx & 31;
        int gm = min(m0 + m, NN - 1);
        float4 v = *(const float4*)&x[(size_t)gm * 128 + kc * 4];
        float* p = &xl[m * 129 + kc * 4];
        p[0] = v.x; p[1] = v.y; p[2] = v.z; p[3] = v.w;
    }
    int tn = tid & 15, tm = tid >> 4;
    float acc[4][4] = {};
    const float4* W4 = (const float4*)W0;
    float4* wl4 = (float4*)wl;
    for (int h = 0; h < 2; ++h) {
        __syncthreads();
#pragma unroll
        for (int i = 0; i < 4; ++i) wl4[i * 256 + tid] = W4[h * 1024 + i * 256 + tid];
        __syncthreads();
#pragma unroll 4
        for (int k = 0; k < 64; ++k) {
            int kk = h * 64 + k;
            float4 wv = *(const float4*)&wl[k * 64 + tn * 4];
            float xv[4];
#pragma unroll
            for (int i = 0; i < 4; ++i) xv[i] = xl[(tm * 4 + i) * 129 + kk];
#pragma unroll
            for (int i = 0; i < 4; ++i) {
                acc[i][0] = fmaf(xv[i], wv.x, acc[i][0]);
                acc[i][1] = fmaf(xv[i], wv.y, acc[i][1]);
                acc[i][2] = fmaf(xv[i], wv.z, acc[i][2]);
                acc[i][3] = fmaf(xv[i], wv.w, acc[i][3]);
            }
        }
    }
#pragma unroll
    for (int i = 0; i < 4; ++i) {
        int m = m0 + tm * 4 + i;
        if (m < NN) {
            float ro = r_out[m];
            US4 o = {f2bf(acc[i][0] * ro), f2bf(acc[i][1] * ro),
                     f2bf(acc[i][2] * ro), f2bf(acc[i][3] * ro)};
            *(US4*)&A[(size_t)m * 64 + tn * 4] = o;
        }
    }
}

// C16(bf16) = ((relu(G @ W1 + b1) @ W2) * r_out).  G is bf16.  64 nodes/block.
__global__ __launch_bounds__(256) void k_mlp(const unsigned short* __restrict__ G,
                                             const float* __restrict__ W1,
                                             const float* __restrict__ b1,
                                             const float* __restrict__ W2,
                                             const float* __restrict__ r_out,
                                             unsigned short* __restrict__ C16) {
    __shared__ float gl[64 * 65];
    __shared__ float w1l[64 * 64];
    __shared__ float w2l[64 * 16];
    int tid = threadIdx.x;
    int m0 = blockIdx.x * 64;
#pragma unroll
    for (int i = 0; i < 2; ++i) {
        int idx = i * 256 + tid;  // 512 chunks of 8 bf16
        int m = idx >> 3, c8 = idx & 7;
        int gm = min(m0 + m, NN - 1);
        uint4 u = *(const uint4*)&G[(size_t)gm * 64 + c8 * 8];
        float* p = &gl[m * 65 + c8 * 8];
        p[0] = bfu(u.x & 0xffffu); p[1] = bfu(u.x >> 16);
        p[2] = bfu(u.y & 0xffffu); p[3] = bfu(u.y >> 16);
        p[4] = bfu(u.z & 0xffffu); p[5] = bfu(u.z >> 16);
        p[6] = bfu(u.w & 0xffffu); p[7] = bfu(u.w >> 16);
    }
    float4* w1l4 = (float4*)w1l;
    const float4* W1_4 = (const float4*)W1;
#pragma unroll
    for (int i = 0; i < 4; ++i) w1l4[i * 256 + tid] = W1_4[i * 256 + tid];
    ((float4*)w2l)[tid] = ((const float4*)W2)[tid];
    __syncthreads();
    int tn = tid & 15, tm = tid >> 4;
    float acc[4][4] = {};
#pragma unroll 4
    for (int k = 0; k < 64; ++k) {
        float4 wv = *(const float4*)&w1l[k * 64 + tn * 4];
        float xv[4];
#pragma unroll
        for (int i = 0; i < 4; ++i) xv[i] = gl[(tm * 4 + i) * 65 + k];
#pragma unroll
        for (int i = 0; i < 4; ++i) {
            acc[i][0] = fmaf(xv[i], wv.x, acc[i][0]);
            acc[i][1] = fmaf(xv[i], wv.y, acc[i][1]);
            acc[i][2] = fmaf(xv[i], wv.z, acc[i][2]);
            acc[i][3] = fmaf(xv[i], wv.w, acc[i][3]);
        }
    }
    float4 bb = *(const float4*)&b1[tn * 4];
    __syncthreads();
#pragma unroll
    for (int i = 0; i < 4; ++i) {
        gl[(tm * 4 + i) * 65 + tn * 4 + 0] = fmaxf(acc[i][0] + bb.x, 0.f);
        gl[(tm * 4 + i) * 65 + tn * 4 + 1] = fmaxf(acc[i][1] + bb.y, 0.f);
        gl[(tm * 4 + i) * 65 + tn * 4 + 2] = fmaxf(acc[i][2] + bb.z, 0.f);
        gl[(tm * 4 + i) * 65 + tn * 4 + 3] = fmaxf(acc[i][3] + bb.w, 0.f);
    }
    __syncthreads();
    int m = tid >> 2, n0 = (tid & 3) * 4;
    float a2[4] = {};
#pragma unroll 8
    for (int k = 0; k < 64; ++k) {
        float zv = gl[m * 65 + k];
        float4 wv = *(const float4*)&w2l[k * 16 + n0];
        a2[0] = fmaf(zv, wv.x, a2[0]);
        a2[1] = fmaf(zv, wv.y, a2[1]);
        a2[2] = fmaf(zv, wv.z, a2[2]);
        a2[3] = fmaf(zv, wv.w, a2[3]);
    }
    int node = m0 + m;
    if (node < NN) {
        float ro = r_out[node];
        US4 o = {f2bf(a2[0] * ro), f2bf(a2[1] * ro), f2bf(a2[2] * ro), f2bf(a2[3] * ro)};
        *(US4*)&C16[(size_t)node * 16 + n0] = o;
    }
}

// ---------------- gathers (bucket edge-parallel, LDS f32 accumulate) ----------------

// d=64 bf16 gather: 1 bucket (128 dst nodes)/block.  Edge-parallel: 8 lanes/edge x
// uint4, 8-deep per group -> 256 edges per block-iteration, zero per-node padding.
// acc[128][65] f32 in LDS (pad 65 spreads banks: bank = (row + 8*f8 + k) & 31).
// MODE 0: also count in-degree -> write r_in; o16 = bf16(relu(agg*r_in+b)*r_out)
// MODE 1: o16 = bf16(agg*r_in)
template <int MODE>
__global__ __launch_bounds__(256) void k_gb64(const int* __restrict__ E2d,
                                              const int* __restrict__ base_d,
                                              const unsigned short* __restrict__ h,
                                              const float* __restrict__ r_inG,
                                              const float* __restrict__ r_out,
                                              const float* __restrict__ bias,
                                              float* __restrict__ r_in_out,
                                              unsigned short* __restrict__ o16) {
    __shared__ float acc[128 * 65];
    __shared__ int cnt[128];
    __shared__ float riS[128];
    int tid = threadIdx.x;
    int b = blockIdx.x;
    int base = base_d[b], m = base_d[b + 1] - base;
    for (int i = tid; i < 128 * 65; i += 256) acc[i] = 0.f;
    if (MODE == 0 && tid < 128) cnt[tid] = 0;
    __syncthreads();
    int g = (tid & 63) >> 3, f8 = tid & 7, w = tid >> 6;
    int ebase = w * 64 + g * 8;  // this group's first edge within a 256-edge chunk
    const unsigned short* hp = h + f8 * 8;
    int it0 = 0;
    for (; it0 + 256 <= m; it0 += 256) {  // full chunks: no clamps, no guards
        const int* ep = E2d + base + it0 + ebase;
        int e[8];
#pragma unroll
        for (int u = 0; u < 8; ++u) e[u] = ep[u];
        uint4 v[8];
#pragma unroll
        for (int u = 0; u < 8; ++u) v[u] = *(const uint4*)(hp + (size_t)(e[u] >> 7) * 64);
        if (MODE == 0 && f8 == 0) {
#pragma unroll
            for (int u = 0; u < 8; ++u) atomicAdd(&cnt[e[u] & 127], 1);
        }
#pragma unroll
        for (int u = 0; u < 8; ++u) {
            float* a = &acc[(e[u] & 127) * 65 + f8 * 8];
            atomicAdd(a + 0, bfu(v[u].x & 0xffffu));
            atomicAdd(a + 1, bfu(v[u].x >> 16));
            atomicAdd(a + 2, bfu(v[u].y & 0xffffu));
            atomicAdd(a + 3, bfu(v[u].y >> 16));
            atomicAdd(a + 4, bfu(v[u].z & 0xffffu));
            atomicAdd(a + 5, bfu(v[u].z >> 16));
            atomicAdd(a + 6, bfu(v[u].w & 0xffffu));
            atomicAdd(a + 7, bfu(v[u].w >> 16));
        }
    }
    if (it0 < m) {  // tail chunk: clamped loads, guarded accumulates
        int idx0 = it0 + ebase;
        int e[8];
#pragma unroll
        for (int u = 0; u < 8; ++u) e[u] = E2d[base + min(idx0 + u, m - 1)];
        uint4 v[8];
#pragma unroll
        for (int u = 0; u < 8; ++u) v[u] = *(const uint4*)(hp + (size_t)(e[u] >> 7) * 64);
        if (MODE == 0 && f8 == 0) {
#pragma unroll
            for (int u = 0; u < 8; ++u)
                if (idx0 + u < m) atomicAdd(&cnt[e[u] & 127], 1);
        }
#pragma unroll
        for (int u = 0; u < 8; ++u) {
            if (idx0 + u < m) {
                float* a = &acc[(e[u] & 127) * 65 + f8 * 8];
                atomicAdd(a + 0, bfu(v[u].x & 0xffffu));
                atomicAdd(a + 1, bfu(v[u].x >> 16));
                atomicAdd(a + 2, bfu(v[u].y & 0xffffu));
                atomicAdd(a + 3, bfu(v[u].y >> 16));
                atomicAdd(a + 4, bfu(v[u].z & 0xffffu));
                atomicAdd(a + 5, bfu(v[u].z >> 16));
                atomicAdd(a + 6, bfu(v[u].w & 0xffffu));
                atomicAdd(a + 7, bfu(v[u].w >> 16));
            }
        }
    }
    __syncthreads();
    if (tid < 128) {
        int node = b * 128 + tid;
        if (MODE == 0) {
            float r = rsqrtf((float)max(cnt[tid], 1));
            riS[tid] = r;
            if (node < NN) r_in_out[node] = r;
        } else {
            riS[tid] = (node < NN) ? r_inG[node] : 0.f;
        }
    }
    __syncthreads();
#pragma unroll
    for (int i = 0; i < 4; ++i) {
        int idx = i * 256 + tid;  // 1024 feature-octets
        int row = idx >> 3, oct = idx & 7;
        int node = b * 128 + row;
        if (node < NN) {
            float ri = riS[row];
            const float* a = &acc[row * 65 + oct * 8];
            unsigned short ov[8];
            if (MODE == 0) {
                float ro = r_out[node];
                float4 bA = *(const float4*)&bias[oct * 8];
                float4 bB = *(const float4*)&bias[oct * 8 + 4];
                float bb[8] = {bA.x, bA.y, bA.z, bA.w, bB.x, bB.y, bB.z, bB.w};
#pragma unroll
                for (int k = 0; k < 8; ++k)
                    ov[k] = f2bf(fmaxf(fmaf(a[k], ri, bb[k]), 0.f) * ro);
            } else {
#pragma unroll
                for (int k = 0; k < 8; ++k) ov[k] = f2bf(a[k] * ri);
            }
            uint4 o;
            o.x = (unsigned)ov[0] | ((unsigned)ov[1] << 16);
            o.y = (unsigned)ov[2] | ((unsigned)ov[3] << 16);
            o.z = (unsigned)ov[4] | ((unsigned)ov[5] << 16);
            o.w = (unsigned)ov[6] | ((unsigned)ov[7] << 16);
            *(uint4*)&o16[(size_t)node * 64 + oct * 8] = o;
        }
    }
}

// d=16 bf16 gather: 1 bucket/block, 4 lanes/edge x uint2, 4-deep per group.
// out = agg*r_in + b2 (fp32)
__global__ __launch_bounds__(256) void k_gb16(const int* __restrict__ E2d,
                                              const int* __restrict__ base_d,
                                              const unsigned short* __restrict__ C16,
                                              const float* __restrict__ r_in,
                                              const float* __restrict__ b2,
                                              float* __restrict__ out) {
    __shared__ float acc[128 * 17];
    int tid = threadIdx.x;
    int b = blockIdx.x;
    int base = base_d[b], m = base_d[b + 1] - base;
    for (int i = tid; i < 128 * 17; i += 256) acc[i] = 0.f;
    __syncthreads();
    int g = (tid & 63) >> 2, f4 = tid & 3, w = tid >> 6;
    int ebase = w * 64 + g * 4;  // 16 groups x 4 edges -> 64 edges per wave-chunk
    const unsigned short* cp = C16 + f4 * 4;
    int it0 = 0;
    for (; it0 + 256 <= m; it0 += 256) {
        const int* ep = E2d + base + it0 + ebase;
        int e[4];
#pragma unroll
        for (int u = 0; u < 4; ++u) e[u] = ep[u];
        uint2 v[4];
#pragma unroll
        for (int u = 0; u < 4; ++u) v[u] = *(const uint2*)(cp + (size_t)(e[u] >> 7) * 16);
#pragma unroll
        for (int u = 0; u < 4; ++u) {
            float* a = &acc[(e[u] & 127) * 17 + f4 * 4];
            atomicAdd(a + 0, bfu(v[u].x & 0xffffu));
            atomicAdd(a + 1, bfu(v[u].x >> 16));
            atomicAdd(a + 2, bfu(v[u].y & 0xffffu));
            atomicAdd(a + 3, bfu(v[u].y >> 16));
        }
    }
    if (it0 < m) {
        int idx0 = it0 + ebase;
        int e[4];
#pragma unroll
        for (int u = 0; u < 4; ++u) e[u] = E2d[base + min(idx0 + u, m - 1)];
        uint2 v[4];
#pragma unroll
        for (int u = 0; u < 4; ++u) v[u] = *(const uint2*)(cp + (size_t)(e[u] >> 7) * 16);
#pragma unroll
        for (int u = 0; u < 4; ++u) {
            if (idx0 + u < m) {
                float* a = &acc[(e[u] & 127) * 17 + f4 * 4];
                atomicAdd(a + 0, bfu(v[u].x & 0xffffu));
                atomicAdd(a + 1, bfu(v[u].x >> 16));
                atomicAdd(a + 2, bfu(v[u].y & 0xffffu));
                atomicAdd(a + 3, bfu(v[u].y >> 16));
            }
        }
    }
    __syncthreads();
#pragma unroll
    for (int i = 0; i < 2; ++i) {
        int idx = i * 256 + tid;  // 512 feature-quads
        int row = idx >> 2, q = idx & 3;
        int node = b * 128 + row;
        if (node < NN) {
            float ri = r_in[node];
            const float* a = &acc[row * 17 + q * 4];
            float4 bb = *(const float4*)&b2[q * 4];
            float4 o;
            o.x = fmaf(a[0], ri, bb.x);
            o.y = fmaf(a[1], ri, bb.y);
            o.z = fmaf(a[2], ri, bb.z);
            o.w = fmaf(a[3], ri, bb.w);
            *(float4*)&out[(size_t)node * 16 + q * 4] = o;
        }
    }
}

extern "C" void kernel_launch(void* const* d_in, const int* in_sizes, int n_in,
                              void* d_out, int out_size, void* d_ws, size_t ws_size,
                              hipStream_t stream) {
    const float* feats = (const float*)d_in[0];
    const int* src = (const int*)d_in[1];
    const int* dst = (const int*)d_in[2];
    const float* W0 = (const float*)d_in[3];
    const float* b0 = (const float*)d_in[4];
    const float* W1 = (const float*)d_in[5];
    const float* b1 = (const float*)d_in[6];
    const float* W2 = (const float*)d_in[7];
    const float* b2 = (const float*)d_in[8];
    float* out = (float*)d_out;

    // ws (4B units):
    //   r_out[NN] | r_in[NN] | E2d[NE] (persistent through all gathers) |
    //   E2s[NE bytes = NE/4] | R1[32NN] (A bf16 then G bf16) | R2[32NN] (B bf16) |
    //   C16[8NN] | base_d[NBUCK+1] cursor_d[NBUCK] base_s[NBUCK+1] cursor_s[NBUCK] |
    //   bcnt8_d[8*NBUCK] bcnt8_s[8*NBUCK]
    float* ws = (float*)d_ws;
    float* r_out = ws;
    float* r_in = ws + NN;
    int* E2d = (int*)(ws + 2 * NN);
    unsigned char* E2s = (unsigned char*)(ws + 2 * NN + NE);
    float* R1 = ws + 2 * NN + NE + NE / 4;
    float* R2 = R1 + (size_t)32 * NN;
    float* Creg = R2 + (size_t)32 * NN;
    int* base_d = (int*)(Creg + (size_t)8 * NN);
    int* cursor_d = base_d + NBUCK + 1;
    int* base_s = cursor_d + NBUCK;
    int* cursor_s = base_s + NBUCK + 1;
    int* bcnt8_d = cursor_s + NBUCK;
    int* bcnt8_s = bcnt8_d + NREP * NBUCK;

    unsigned short* A = (unsigned short*)R1;
    unsigned short* G = A;  // after k_gb64<0> consumes A, region reused for G
    unsigned short* B = (unsigned short*)R2;
    unsigned short* C16 = (unsigned short*)Creg;

    // build (no CSR: E2d itself drives all gathers)
    hipMemsetAsync(bcnt8_d, 0, 2 * NREP * NBUCK * sizeof(int), stream);
    k_hist<<<HISTB, 256, 0, stream>>>(src, dst, bcnt8_d, bcnt8_s);
    k_bscan<<<2, 1024, 0, stream>>>(bcnt8_d, bcnt8_s, base_d, cursor_d, base_s, cursor_s);
    k_pairs<<<(NE + PCHUNK - 1) / PCHUNK, 256, 0, stream>>>(src, dst, cursor_d, cursor_s,
                                                            E2d, E2s);
    k_out<<<NBUCK, 256, 0, stream>>>(E2s, base_s, r_out);

    // layer 0
    k_gemm0<<<(NN + 63) / 64, 256, 0, stream>>>(feats, W0, r_out, A);
    k_gb64<0><<<NBUCK, 256, 0, stream>>>(E2d, base_d, A, r_in, r_out, b0, r_in, B);

    // layer 1 (+ layer2 pre-GEMM)
    k_gb64<1><<<NBUCK, 256, 0, stream>>>(E2d, base_d, B, r_in, r_out, b0, r_in, G);
    k_mlp<<<(NN + 63) / 64, 256, 0, stream>>>(G, W1, b1, W2, r_out, C16);

    // layer 2
    k_gb16<<<NBUCK, 256, 0, stream>>>(E2d, base_d, C16, r_in, b2, out);
}

// Round 2
// 356.965 us; speedup vs baseline: 4.8797x; 4.8797x over previous
//
#include <hip/hip_runtime.h>

#define NN 100000
#define NE 1600000
#define NBUCK 782   // ceil(NN/128), bucket = node >> 7
#define PCHUNK 4096 // edges per k_pairs block -> 391 blocks
#define HISTB 256   // k_hist grid
#define NREP 8      // replicated bucket-count copies
#define STAGE_CAP 12288 // k_nodes LDS staging (48 KB; bucket mean 2046, sigma ~45 -> never exceeded)

struct alignas(8) US4 { unsigned short x, y, z, w; };

__device__ __forceinline__ float bfu(unsigned int hw) { return __uint_as_float(hw << 16); }
__device__ __forceinline__ unsigned short f2bf(float f) {
    unsigned int u = __float_as_uint(f);
    return (unsigned short)((u + 0x7fffu + ((u >> 16) & 1u)) >> 16);
}

// ---------------- build: dual bucket-ordered edge arrays ----------------

// LDS-only dual histogram (dst buckets + src buckets), replicated global merge.
__global__ __launch_bounds__(256) void k_hist(const int* __restrict__ src,
                                              const int* __restrict__ dst,
                                              int* __restrict__ bcnt8_d,
                                              int* __restrict__ bcnt8_s) {
    __shared__ int hd[NBUCK], hs[NBUCK];
    int tid = threadIdx.x;
    for (int i = tid; i < NBUCK; i += 256) { hd[i] = 0; hs[i] = 0; }
    __syncthreads();
    int* md = bcnt8_d + (size_t)(blockIdx.x & (NREP - 1)) * NBUCK;
    int* ms = bcnt8_s + (size_t)(blockIdx.x & (NREP - 1)) * NBUCK;
    int stride = gridDim.x * 256;
    for (int e = blockIdx.x * 256 + tid; e < NE; e += stride) {
        atomicAdd(&hd[dst[e] >> 7], 1);
        atomicAdd(&hs[src[e] >> 7], 1);
    }
    __syncthreads();
    for (int i = tid; i < NBUCK; i += 256) {
        if (hd[i]) atomicAdd(&md[i], hd[i]);
        if (hs[i]) atomicAdd(&ms[i], hs[i]);
    }
}

// block 0: scan dst buckets; block 1: scan src buckets
__global__ __launch_bounds__(1024) void k_bscan(const int* __restrict__ bcnt8_d,
                                                const int* __restrict__ bcnt8_s,
                                                int* __restrict__ base_d,
                                                int* __restrict__ cursor_d,
                                                int* __restrict__ base_s,
                                                int* __restrict__ cursor_s) {
    __shared__ int tmp[1024];
    int t = threadIdx.x;
    const int* bc = blockIdx.x ? bcnt8_s : bcnt8_d;
    int* base = blockIdx.x ? base_s : base_d;
    int* cur = blockIdx.x ? cursor_s : cursor_d;
    int v = 0;
    if (t < NBUCK)
#pragma unroll
        for (int c = 0; c < NREP; ++c) v += bc[c * NBUCK + t];
    tmp[t] = v;
    __syncthreads();
    for (int off = 1; off < 1024; off <<= 1) {
        int u = (t >= off) ? tmp[t - off] : 0;
        __syncthreads();
        tmp[t] += u;
        __syncthreads();
    }
    int excl = tmp[t] - v;
    if (t < NBUCK) {
        base[t] = excl;
        cur[t] = excl;
    }
    if (t == 0) base[NBUCK] = NE;
}

// dual LDS-binned scatter: bulk reservation per (block,bucket), packed words
// into per-block contiguous runs.  E2d = (src<<7)|(dst&127); E2s = src&127 (byte).
__global__ __launch_bounds__(256) void k_pairs(const int* __restrict__ src,
                                               const int* __restrict__ dst,
                                               int* __restrict__ cursor_d,
                                               int* __restrict__ cursor_s,
                                               int* __restrict__ E2d,
                                               unsigned char* __restrict__ E2s) {
    __shared__ int hist_d[NBUCK], gbase_d[NBUCK], hist_s[NBUCK], gbase_s[NBUCK];
    int tid = threadIdx.x;
    for (int i = tid; i < NBUCK; i += 256) { hist_d[i] = 0; hist_s[i] = 0; }
    __syncthreads();
    int base = blockIdx.x * PCHUNK;
#pragma unroll
    for (int i = 0; i < PCHUNK / 256; ++i) {
        int e = base + i * 256 + tid;
        if (e < NE) {
            atomicAdd(&hist_d[dst[e] >> 7], 1);
            atomicAdd(&hist_s[src[e] >> 7], 1);
        }
    }
    __syncthreads();
    // rotate reservation start per block to decorrelate cursor-line contention
    int rot = (int)((blockIdx.x * 191u) % NBUCK);
    for (int ii = tid; ii < NBUCK; ii += 256) {
        int i = ii + rot;
        if (i >= NBUCK) i -= NBUCK;
        int h = hist_d[i];
        if (h) gbase_d[i] = atomicAdd(&cursor_d[i], h);
        hist_d[i] = 0;
        h = hist_s[i];
        if (h) gbase_s[i] = atomicAdd(&cursor_s[i], h);
        hist_s[i] = 0;
    }
    __syncthreads();
#pragma unroll
    for (int i = 0; i < PCHUNK / 256; ++i) {
        int e = base + i * 256 + tid;
        if (e < NE) {
            int s = src[e], d = dst[e];
            int bd = d >> 7;
            int pd = atomicAdd(&hist_d[bd], 1);
            E2d[gbase_d[bd] + pd] = (s << 7) | (d & 127);
            int bs = s >> 7;
            int ps = atomicAdd(&hist_s[bs], 1);
            E2s[gbase_s[bs] + ps] = (unsigned char)(s & 127);
        }
    }
}

// out-degree only (src buckets): r_out = rsqrt(max(deg_out,1))
__global__ __launch_bounds__(256) void k_out(const unsigned char* __restrict__ E2s,
                                             const int* __restrict__ base_s,
                                             float* __restrict__ r_out) {
    __shared__ int cnt[128];
    int tid = threadIdx.x;
    int b = blockIdx.x;
    int base = base_s[b], end = base_s[b + 1];
    if (tid < 128) cnt[tid] = 0;
    __syncthreads();
    for (int i = base + tid; i < end; i += 256) atomicAdd(&cnt[E2s[i]], 1);
    __syncthreads();
    if (tid < 128) {
        int node = b * 128 + tid;
        if (node < NN) r_out[node] = rsqrtf((float)max(cnt[tid], 1));
    }
}

// per-bucket CSR built IN PLACE over E2d (bucket fully staged in LDS first).
// rowdesc[node] = (abs_row_start << 9) | deg   (deg < 512 guaranteed; Poisson(16))
__global__ __launch_bounds__(256) void k_nodes(int* __restrict__ EB,
                                               const int* __restrict__ base_d,
                                               int* __restrict__ rowdesc,
                                               float* __restrict__ r_in) {
    __shared__ int cnt[128], cur[128];
    __shared__ int stage[STAGE_CAP];  // 48 KB
    int tid = threadIdx.x;
    int b = blockIdx.x;
    int base = base_d[b], end = base_d[b + 1];
    int m = min(end - base, STAGE_CAP);  // cap: statistically impossible to exceed
    if (tid < 128) cnt[tid] = 0;
    __syncthreads();
    for (int i = tid; i < m; i += 256) {
        int e = EB[base + i];
        stage[i] = e;
        atomicAdd(&cnt[e & 127], 1);
    }
    __syncthreads();
    int v = (tid < 128) ? cnt[tid] : 0;
    for (int off = 1; off < 128; off <<= 1) {
        int u = (tid >= off && tid < 128) ? cnt[tid - off] : 0;
        __syncthreads();
        if (tid < 128) cnt[tid] += u;
        __syncthreads();
    }
    if (tid < 128) {
        int excl = cnt[tid] - v;  // exclusive scan within bucket
        cur[tid] = excl;
        int node = b * 128 + tid;
        if (node < NN) {
            rowdesc[node] = ((base + excl) << 9) | min(v, 511);
            r_in[node] = rsqrtf((float)max(v, 1));
        }
    }
    __syncthreads();
    for (int i = tid; i < m; i += 256) {
        int e = stage[i];
        int pos = atomicAdd(&cur[e & 127], 1);
        EB[base + pos] = e >> 7;
    }
}

// zero dummy rows (index NN) of all gathered tables + csr tail guard.
__global__ void k_zrow(unsigned short* __restrict__ A, unsigned short* __restrict__ B,
                       unsigned short* __restrict__ C16, int* __restrict__ csr) {
    int t = threadIdx.x;  // 64 threads
    A[(size_t)NN * 64 + t] = 0;
    B[(size_t)NN * 64 + t] = 0;
    if (t < 16) C16[(size_t)NN * 16 + t] = 0;
    if (t < 16) csr[NE + t] = NN;  // prefetch-beyond guard at array end
}

// ---------------- dense GEMMs ----------------

// A(bf16) = (x @ W0) * r_out.  64 nodes/block, thread = 4m x 4n, K=128 in two halves.
__global__ __launch_bounds__(256) void k_gemm0(const float* __restrict__ x,
                                               const float* __restrict__ W0,
                                               const float* __restrict__ r_out,
                                               unsigned short* __restrict__ A) {
    __shared__ float xl[64 * 129];
    __shared__ float wl[64 * 64];
    int tid = threadIdx.x;
    int m0 = blockIdx.x * 64;
#pragma unroll
    for (int i = 0; i < 8; ++i) {
        int idx = i * 256 + tid;
        int m = idx >> 5, kc = idx & 31;
        int gm = min(m0 + m, NN - 1);
        float4 v = *(const float4*)&x[(size_t)gm * 128 + kc * 4];
        float* p = &xl[m * 129 + kc * 4];
        p[0] = v.x; p[1] = v.y; p[2] = v.z; p[3] = v.w;
    }
    int tn = tid & 15, tm = tid >> 4;
    float acc[4][4] = {};
    const float4* W4 = (const float4*)W0;
    float4* wl4 = (float4*)wl;
    for (int h = 0; h < 2; ++h) {
        __syncthreads();
#pragma unroll
        for (int i = 0; i < 4; ++i) wl4[i * 256 + tid] = W4[h * 1024 + i * 256 + tid];
        __syncthreads();
#pragma unroll 4
        for (int k = 0; k < 64; ++k) {
            int kk = h * 64 + k;
            float4 wv = *(const float4*)&wl[k * 64 + tn * 4];
            float xv[4];
#pragma unroll
            for (int i = 0; i < 4; ++i) xv[i] = xl[(tm * 4 + i) * 129 + kk];
#pragma unroll
            for (int i = 0; i < 4; ++i) {
                acc[i][0] = fmaf(xv[i], wv.x, acc[i][0]);
                acc[i][1] = fmaf(xv[i], wv.y, acc[i][1]);
                acc[i][2] = fmaf(xv[i], wv.z, acc[i][2]);
                acc[i][3] = fmaf(xv[i], wv.w, acc[i][3]);
            }
        }
    }
#pragma unroll
    for (int i = 0; i < 4; ++i) {
        int m = m0 + tm * 4 + i;
        if (m < NN) {
            float ro = r_out[m];
            US4 o = {f2bf(acc[i][0] * ro), f2bf(acc[i][1] * ro),
                     f2bf(acc[i][2] * ro), f2bf(acc[i][3] * ro)};
            *(US4*)&A[(size_t)m * 64 + tn * 4] = o;
        }
    }
}

// C16(bf16) = ((relu(G @ W1 + b1) @ W2) * r_out).  G is bf16.  64 nodes/block.
__global__ __launch_bounds__(256) void k_mlp(const unsigned short* __restrict__ G,
                                             const float* __restrict__ W1,
                                             const float* __restrict__ b1,
                                             const float* __restrict__ W2,
                                             const float* __restrict__ r_out,
                                             unsigned short* __restrict__ C16) {
    __shared__ float gl[64 * 65];
    __shared__ float w1l[64 * 64];
    __shared__ float w2l[64 * 16];
    int tid = threadIdx.x;
    int m0 = blockIdx.x * 64;
#pragma unroll
    for (int i = 0; i < 2; ++i) {
        int idx = i * 256 + tid;  // 512 chunks of 8 bf16
        int m = idx >> 3, c8 = idx & 7;
        int gm = min(m0 + m, NN - 1);
        uint4 u = *(const uint4*)&G[(size_t)gm * 64 + c8 * 8];
        float* p = &gl[m * 65 + c8 * 8];
        p[0] = bfu(u.x & 0xffffu); p[1] = bfu(u.x >> 16);
        p[2] = bfu(u.y & 0xffffu); p[3] = bfu(u.y >> 16);
        p[4] = bfu(u.z & 0xffffu); p[5] = bfu(u.z >> 16);
        p[6] = bfu(u.w & 0xffffu); p[7] = bfu(u.w >> 16);
    }
    float4* w1l4 = (float4*)w1l;
    const float4* W1_4 = (const float4*)W1;
#pragma unroll
    for (int i = 0; i < 4; ++i) w1l4[i * 256 + tid] = W1_4[i * 256 + tid];
    ((float4*)w2l)[tid] = ((const float4*)W2)[tid];
    __syncthreads();
    int tn = tid & 15, tm = tid >> 4;
    float acc[4][4] = {};
#pragma unroll 4
    for (int k = 0; k < 64; ++k) {
        float4 wv = *(const float4*)&w1l[k * 64 + tn * 4];
        float xv[4];
#pragma unroll
        for (int i = 0; i < 4; ++i) xv[i] = gl[(tm * 4 + i) * 65 + k];
#pragma unroll
        for (int i = 0; i < 4; ++i) {
            acc[i][0] = fmaf(xv[i], wv.x, acc[i][0]);
            acc[i][1] = fmaf(xv[i], wv.y, acc[i][1]);
            acc[i][2] = fmaf(xv[i], wv.z, acc[i][2]);
            acc[i][3] = fmaf(xv[i], wv.w, acc[i][3]);
        }
    }
    float4 bb = *(const float4*)&b1[tn * 4];
    __syncthreads();
#pragma unroll
    for (int i = 0; i < 4; ++i) {
        gl[(tm * 4 + i) * 65 + tn * 4 + 0] = fmaxf(acc[i][0] + bb.x, 0.f);
        gl[(tm * 4 + i) * 65 + tn * 4 + 1] = fmaxf(acc[i][1] + bb.y, 0.f);
        gl[(tm * 4 + i) * 65 + tn * 4 + 2] = fmaxf(acc[i][2] + bb.z, 0.f);
        gl[(tm * 4 + i) * 65 + tn * 4 + 3] = fmaxf(acc[i][3] + bb.w, 0.f);
    }
    __syncthreads();
    int m = tid >> 2, n0 = (tid & 3) * 4;
    float a2[4] = {};
#pragma unroll 8
    for (int k = 0; k < 64; ++k) {
        float zv = gl[m * 65 + k];
        float4 wv = *(const float4*)&w2l[k * 16 + n0];
        a2[0] = fmaf(zv, wv.x, a2[0]);
        a2[1] = fmaf(zv, wv.y, a2[1]);
        a2[2] = fmaf(zv, wv.z, a2[2]);
        a2[3] = fmaf(zv, wv.w, a2[3]);
    }
    int node = m0 + m;
    if (node < NN) {
        float ro = r_out[node];
        US4 o = {f2bf(a2[0] * ro), f2bf(a2[1] * ro), f2bf(a2[2] * ro), f2bf(a2[3] * ro)};
        *(US4*)&C16[(size_t)node * 16 + n0] = o;
    }
}

// ---------------- gathers (register-accumulate, per-node wave) ----------------

// d=64 bf16 gather, 1 node/wave.  8 lanes/edge x uint4; PAIRS of 8-edge steps
// (16 edges/iter, 2 loads in flight) + single-step tail.  Tail lanes read the
// zero dummy row (index NN) instead of clamp+weight: no min/cmp per edge.
// MODE 0: o16 = bf16(relu(agg*r_in + bias)*r_out)   (layer0 -> B)
// MODE 1: o16 = bf16(agg*r_in)                      (layer1 -> G, feeds k_mlp)
template <int MODE>
__global__ __launch_bounds__(256) void k_gb64(const int* __restrict__ rowdesc,
                                              const int* __restrict__ csr,
                                              const unsigned short* __restrict__ h,
                                              const float* __restrict__ r_in,
                                              const float* __restrict__ r_out,
                                              const float* __restrict__ bias,
                                              unsigned short* __restrict__ o16) {
    int tid = threadIdx.x;
    int wave = tid >> 6, lane = tid & 63;
    int n = blockIdx.x * 4 + wave;
    int rd = rowdesc[n];
    int jb = rd >> 9, deg = rd & 511;
    int nst = (deg + 7) >> 3;
    int g = lane >> 3, f8 = lane & 7;  // g: edge slot in step [0,8), f8: feature octet
    const int* ep = csr + jb + g;
    const unsigned short* hp = h + f8 * 8;
    float a[8] = {};
    int idx = g + 8;  // edge index of second-of-pair
    for (int st = 0; st + 2 <= nst; st += 2, idx += 16) {
        int ea = ep[st * 8];       // first of pair: provably in-range, no select
        int eb = ep[st * 8 + 8];
        eb = (idx < deg) ? eb : NN;
        uint4 ua = *(const uint4*)(hp + (size_t)ea * 64);
        uint4 ub = *(const uint4*)(hp + (size_t)eb * 64);
        a[0] += bfu(ua.x & 0xffffu); a[1] += bfu(ua.x >> 16);
        a[2] += bfu(ua.y & 0xffffu); a[3] += bfu(ua.y >> 16);
        a[4] += bfu(ua.z & 0xffffu); a[5] += bfu(ua.z >> 16);
        a[6] += bfu(ua.w & 0xffffu); a[7] += bfu(ua.w >> 16);
        a[0] += bfu(ub.x & 0xffffu); a[1] += bfu(ub.x >> 16);
        a[2] += bfu(ub.y & 0xffffu); a[3] += bfu(ub.y >> 16);
        a[4] += bfu(ub.z & 0xffffu); a[5] += bfu(ub.z >> 16);
        a[6] += bfu(ub.w & 0xffffu); a[7] += bfu(ub.w >> 16);
    }
    if (nst & 1) {  // tail single step
        int st = nst - 1;
        int e = ep[st * 8];
        e = (st * 8 + g < deg) ? e : NN;
        uint4 u = *(const uint4*)(hp + (size_t)e * 64);
        a[0] += bfu(u.x & 0xffffu); a[1] += bfu(u.x >> 16);
        a[2] += bfu(u.y & 0xffffu); a[3] += bfu(u.y >> 16);
        a[4] += bfu(u.z & 0xffffu); a[5] += bfu(u.z >> 16);
        a[6] += bfu(u.w & 0xffffu); a[7] += bfu(u.w >> 16);
    }
#pragma unroll
    for (int m = 8; m <= 32; m <<= 1) {
#pragma unroll
        for (int k = 0; k < 8; ++k) a[k] += __shfl_xor(a[k], m);
    }
    if (g == 0) {
        float ri = r_in[n];
        unsigned short ov[8];
        if (MODE == 0) {
            float ro = r_out[n];
            float4 bA = *(const float4*)&bias[f8 * 8];
            float4 bB = *(const float4*)&bias[f8 * 8 + 4];
            float bb[8] = {bA.x, bA.y, bA.z, bA.w, bB.x, bB.y, bB.z, bB.w};
#pragma unroll
            for (int k = 0; k < 8; ++k)
                ov[k] = f2bf(fmaxf(fmaf(a[k], ri, bb[k]), 0.f) * ro);
        } else {
#pragma unroll
            for (int k = 0; k < 8; ++k) ov[k] = f2bf(a[k] * ri);
        }
        uint4 o;
        o.x = (unsigned)ov[0] | ((unsigned)ov[1] << 16);
        o.y = (unsigned)ov[2] | ((unsigned)ov[3] << 16);
        o.z = (unsigned)ov[4] | ((unsigned)ov[5] << 16);
        o.w = (unsigned)ov[6] | ((unsigned)ov[7] << 16);
        *(uint4*)&o16[(size_t)n * 64 + f8 * 8] = o;
    }
}

// d=16 bf16 gather: 8 lanes/edge x uint (2 feats), same pair-step structure.
// out = agg*r_in + b2 (fp32 output)
__global__ __launch_bounds__(256) void k_gb16(const int* __restrict__ rowdesc,
                                              const int* __restrict__ csr,
                                              const unsigned short* __restrict__ C16,
                                              const float* __restrict__ r_in,
                                              const float* __restrict__ b2,
                                              float* __restrict__ out) {
    int tid = threadIdx.x;
    int wave = tid >> 6, lane = tid & 63;
    int n = blockIdx.x * 4 + wave;
    int rd = rowdesc[n];
    int jb = rd >> 9, deg = rd & 511;
    int nst = (deg + 7) >> 3;
    int g = lane >> 3, p = lane & 7;  // p: feature pair [0,8)
    const int* ep = csr + jb + g;
    const unsigned short* cp = C16 + p * 2;
    float a0 = 0.f, a1 = 0.f;
    int idx = g + 8;
    for (int st = 0; st + 2 <= nst; st += 2, idx += 16) {
        int ea = ep[st * 8];
        int eb = ep[st * 8 + 8];
        eb = (idx < deg) ? eb : NN;
        unsigned ua = *(const unsigned*)(cp + (size_t)ea * 16);
        unsigned ub = *(const unsigned*)(cp + (size_t)eb * 16);
        a0 += bfu(ua & 0xffffu); a1 += bfu(ua >> 16);
        a0 += bfu(ub & 0xffffu); a1 += bfu(ub >> 16);
    }
    if (nst & 1) {
        int st = nst - 1;
        int e = ep[st * 8];
        e = (st * 8 + g < deg) ? e : NN;
        unsigned u = *(const unsigned*)(cp + (size_t)e * 16);
        a0 += bfu(u & 0xffffu); a1 += bfu(u >> 16);
    }
#pragma unroll
    for (int m = 8; m <= 32; m <<= 1) {
        a0 += __shfl_xor(a0, m);
        a1 += __shfl_xor(a1, m);
    }
    if (g == 0) {
        float ri = r_in[n];
        float2 bb = *(const float2*)&b2[p * 2];
        float2 o;
        o.x = fmaf(a0, ri, bb.x);
        o.y = fmaf(a1, ri, bb.y);
        *(float2*)&out[(size_t)n * 16 + p * 2] = o;
    }
}

extern "C" void kernel_launch(void* const* d_in, const int* in_sizes, int n_in,
                              void* d_out, int out_size, void* d_ws, size_t ws_size,
                              hipStream_t stream) {
    const float* feats = (const float*)d_in[0];
    const int* src = (const int*)d_in[1];
    const int* dst = (const int*)d_in[2];
    const float* W0 = (const float*)d_in[3];
    const float* b0 = (const float*)d_in[4];
    const float* W1 = (const float*)d_in[5];
    const float* b1 = (const float*)d_in[6];
    const float* W2 = (const float*)d_in[7];
    const float* b2 = (const float*)d_in[8];
    float* out = (float*)d_out;

    // ws (4B units):
    //   r_out[NN] | r_in[NN] | rowdesc[NN] | EB[NE+16] (E2d then csr in-place, +guard) |
    //   E2s[NE bytes = NE/4] | R1[32(NN+1)] (A bf16 then G bf16) | R2[32(NN+1)] (B bf16) |
    //   C16[8(NN+1)] | base_d[NBUCK+1] cursor_d[NBUCK] base_s[NBUCK+1] cursor_s[NBUCK] |
    //   bcnt8_d[8*NBUCK] bcnt8_s[8*NBUCK]
    float* ws = (float*)d_ws;
    float* r_out = ws;
    float* r_in = ws + NN;
    int* rowdesc = (int*)(ws + 2 * NN);
    int* EB = (int*)(ws + 3 * NN);  // NE + 16
    unsigned char* E2s = (unsigned char*)(ws + 3 * NN + NE + 16);
    float* R1 = ws + 3 * NN + NE + 16 + NE / 4;
    float* R2 = R1 + (size_t)32 * (NN + 1);
    float* Creg = R2 + (size_t)32 * (NN + 1);
    int* base_d = (int*)(Creg + (size_t)8 * (NN + 1));
    int* cursor_d = base_d + NBUCK + 1;
    int* base_s = cursor_d + NBUCK;
    int* cursor_s = base_s + NBUCK + 1;
    int* bcnt8_d = cursor_s + NBUCK;
    int* bcnt8_s = bcnt8_d + NREP * NBUCK;

    unsigned short* A = (unsigned short*)R1;
    unsigned short* G = A;  // after k_gb64<0> consumes A, region reused for G
    unsigned short* B = (unsigned short*)R2;
    unsigned short* C16 = (unsigned short*)Creg;

    // build (CSR in place over the bucket-ordered edge array)
    hipMemsetAsync(bcnt8_d, 0, 2 * NREP * NBUCK * sizeof(int), stream);
    k_zrow<<<1, 64, 0, stream>>>(A, B, C16, EB);
    k_hist<<<HISTB, 256, 0, stream>>>(src, dst, bcnt8_d, bcnt8_s);
    k_bscan<<<2, 1024, 0, stream>>>(bcnt8_d, bcnt8_s, base_d, cursor_d, base_s, cursor_s);
    k_pairs<<<(NE + PCHUNK - 1) / PCHUNK, 256, 0, stream>>>(src, dst, cursor_d, cursor_s,
                                                            EB, E2s);
    k_out<<<NBUCK, 256, 0, stream>>>(E2s, base_s, r_out);
    k_nodes<<<NBUCK, 256, 0, stream>>>(EB, base_d, rowdesc, r_in);

    // layer 0
    k_gemm0<<<(NN + 63) / 64, 256, 0, stream>>>(feats, W0, r_out, A);
    k_gb64<0><<<NN / 4, 256, 0, stream>>>(rowdesc, EB, A, r_in, r_out, b0, B);

    // layer 1 (+ layer2 pre-GEMM)
    k_gb64<1><<<NN / 4, 256, 0, stream>>>(rowdesc, EB, B, r_in, r_out, b0, G);
    k_mlp<<<(NN + 63) / 64, 256, 0, stream>>>(G, W1, b1, W2, r_out, C16);

    // layer 2
    k_gb16<<<NN / 4, 256, 0, stream>>>(rowdesc, EB, C16, r_in, b2, out);
}

// Round 3
// 342.198 us; speedup vs baseline: 5.0903x; 1.0432x over previous
//
#include <hip/hip_runtime.h>

#define NN 100000
#define NE 1600000
#define NBUCK 782   // ceil(NN/128), bucket = node >> 7
#define PCHUNK 4096 // edges per k_pairs block -> 391 blocks
#define HISTB 256   // k_hist grid
#define NREP 8      // replicated bucket-count copies
#define STAGE_CAP 12288 // k_nodes LDS staging (48 KB; bucket mean 2046, sigma ~45)

struct alignas(8) US4 { unsigned short x, y, z, w; };

__device__ __forceinline__ float bfu(unsigned int hw) { return __uint_as_float(hw << 16); }
__device__ __forceinline__ unsigned short f2bf(float f) {
    unsigned int u = __float_as_uint(f);
    return (unsigned short)((u + 0x7fffu + ((u >> 16) & 1u)) >> 16);
}

// ---------------- build: dual bucket-ordered edge arrays ----------------

// LDS-only dual histogram (dst buckets + src buckets), replicated global merge.
__global__ __launch_bounds__(256) void k_hist(const int* __restrict__ src,
                                              const int* __restrict__ dst,
                                              int* __restrict__ bcnt8_d,
                                              int* __restrict__ bcnt8_s) {
    __shared__ int hd[NBUCK], hs[NBUCK];
    int tid = threadIdx.x;
    for (int i = tid; i < NBUCK; i += 256) { hd[i] = 0; hs[i] = 0; }
    __syncthreads();
    int* md = bcnt8_d + (size_t)(blockIdx.x & (NREP - 1)) * NBUCK;
    int* ms = bcnt8_s + (size_t)(blockIdx.x & (NREP - 1)) * NBUCK;
    int stride = gridDim.x * 256;
    for (int e = blockIdx.x * 256 + tid; e < NE; e += stride) {
        atomicAdd(&hd[dst[e] >> 7], 1);
        atomicAdd(&hs[src[e] >> 7], 1);
    }
    __syncthreads();
    for (int i = tid; i < NBUCK; i += 256) {
        if (hd[i]) atomicAdd(&md[i], hd[i]);
        if (hs[i]) atomicAdd(&ms[i], hs[i]);
    }
}

// blocks 0/1: scan dst/src buckets; block 2: zero dummy rows + csr guard.
__global__ __launch_bounds__(1024) void k_bscan(const int* __restrict__ bcnt8_d,
                                                const int* __restrict__ bcnt8_s,
                                                int* __restrict__ base_d,
                                                int* __restrict__ cursor_d,
                                                int* __restrict__ base_s,
                                                int* __restrict__ cursor_s,
                                                unsigned short* __restrict__ A,
                                                unsigned short* __restrict__ B,
                                                unsigned short* __restrict__ C16,
                                                int* __restrict__ EBg) {
    if (blockIdx.x == 2) {
        int t = threadIdx.x;
        if (t < 64) {
            A[(size_t)NN * 64 + t] = 0;
            B[(size_t)NN * 64 + t] = 0;
        }
        if (t < 16) {
            C16[(size_t)NN * 16 + t] = 0;
            EBg[NE + t] = NN;
        }
        return;
    }
    __shared__ int tmp[1024];
    int t = threadIdx.x;
    const int* bc = blockIdx.x ? bcnt8_s : bcnt8_d;
    int* base = blockIdx.x ? base_s : base_d;
    int* cur = blockIdx.x ? cursor_s : cursor_d;
    int v = 0;
    if (t < NBUCK)
#pragma unroll
        for (int c = 0; c < NREP; ++c) v += bc[c * NBUCK + t];
    tmp[t] = v;
    __syncthreads();
    for (int off = 1; off < 1024; off <<= 1) {
        int u = (t >= off) ? tmp[t - off] : 0;
        __syncthreads();
        tmp[t] += u;
        __syncthreads();
    }
    int excl = tmp[t] - v;
    if (t < NBUCK) {
        base[t] = excl;
        cur[t] = excl;
    }
    if (t == 0) base[NBUCK] = NE;
}

// dual LDS-binned scatter: bulk reservation per (block,bucket), packed words
// into per-block contiguous runs.  E2d = (src<<7)|(dst&127); E2s = src&127 (byte).
__global__ __launch_bounds__(256) void k_pairs(const int* __restrict__ src,
                                               const int* __restrict__ dst,
                                               int* __restrict__ cursor_d,
                                               int* __restrict__ cursor_s,
                                               int* __restrict__ E2d,
                                               unsigned char* __restrict__ E2s) {
    __shared__ int hist_d[NBUCK], gbase_d[NBUCK], hist_s[NBUCK], gbase_s[NBUCK];
    int tid = threadIdx.x;
    for (int i = tid; i < NBUCK; i += 256) { hist_d[i] = 0; hist_s[i] = 0; }
    __syncthreads();
    int base = blockIdx.x * PCHUNK;
#pragma unroll
    for (int i = 0; i < PCHUNK / 256; ++i) {
        int e = base + i * 256 + tid;
        if (e < NE) {
            atomicAdd(&hist_d[dst[e] >> 7], 1);
            atomicAdd(&hist_s[src[e] >> 7], 1);
        }
    }
    __syncthreads();
    // rotate reservation start per block to decorrelate cursor-line contention
    int rot = (int)((blockIdx.x * 191u) % NBUCK);
    for (int ii = tid; ii < NBUCK; ii += 256) {
        int i = ii + rot;
        if (i >= NBUCK) i -= NBUCK;
        int h = hist_d[i];
        if (h) gbase_d[i] = atomicAdd(&cursor_d[i], h);
        hist_d[i] = 0;
        h = hist_s[i];
        if (h) gbase_s[i] = atomicAdd(&cursor_s[i], h);
        hist_s[i] = 0;
    }
    __syncthreads();
#pragma unroll
    for (int i = 0; i < PCHUNK / 256; ++i) {
        int e = base + i * 256 + tid;
        if (e < NE) {
            int s = src[e], d = dst[e];
            int bd = d >> 7;
            int pd = atomicAdd(&hist_d[bd], 1);
            E2d[gbase_d[bd] + pd] = (s << 7) | (d & 127);
            int bs = s >> 7;
            int ps = atomicAdd(&hist_s[bs], 1);
            E2s[gbase_s[bs] + ps] = (unsigned char)(s & 127);
        }
    }
}

// b < NBUCK: per-bucket CSR built IN PLACE over EB (bucket staged in LDS) +
//            rowdesc[node] = (abs_row_start << 9) | deg, r_in.
// b >= NBUCK: out-degree count from E2s -> r_out.
__global__ __launch_bounds__(256) void k_nodes(int* __restrict__ EB,
                                               const int* __restrict__ base_d,
                                               const unsigned char* __restrict__ E2s,
                                               const int* __restrict__ base_s,
                                               int* __restrict__ rowdesc,
                                               float* __restrict__ r_in,
                                               float* __restrict__ r_out) {
    __shared__ int cnt[128], cur[128];
    __shared__ int stage[STAGE_CAP];  // 48 KB
    int tid = threadIdx.x;
    int b = blockIdx.x;
    if (b >= NBUCK) {  // ---- out-degree ----
        b -= NBUCK;
        int base = base_s[b], end = base_s[b + 1];
        if (tid < 128) cnt[tid] = 0;
        __syncthreads();
        for (int i = base + tid; i < end; i += 256) atomicAdd(&cnt[E2s[i]], 1);
        __syncthreads();
        if (tid < 128) {
            int node = b * 128 + tid;
            if (node < NN) r_out[node] = rsqrtf((float)max(cnt[tid], 1));
        }
        return;
    }
    int base = base_d[b], end = base_d[b + 1];
    int m = min(end - base, STAGE_CAP);  // cap: statistically impossible to exceed
    if (tid < 128) cnt[tid] = 0;
    __syncthreads();
    for (int i = tid; i < m; i += 256) {
        int e = EB[base + i];
        stage[i] = e;
        atomicAdd(&cnt[e & 127], 1);
    }
    __syncthreads();
    int v = (tid < 128) ? cnt[tid] : 0;
    for (int off = 1; off < 128; off <<= 1) {
        int u = (tid >= off && tid < 128) ? cnt[tid - off] : 0;
        __syncthreads();
        if (tid < 128) cnt[tid] += u;
        __syncthreads();
    }
    if (tid < 128) {
        int excl = cnt[tid] - v;  // exclusive scan within bucket
        cur[tid] = excl;
        int node = b * 128 + tid;
        if (node < NN) {
            rowdesc[node] = ((base + excl) << 9) | min(v, 511);
            r_in[node] = rsqrtf((float)max(v, 1));
        }
    }
    __syncthreads();
    for (int i = tid; i < m; i += 256) {
        int e = stage[i];
        int pos = atomicAdd(&cur[e & 127], 1);
        EB[base + pos] = e >> 7;
    }
}

// ---------------- dense GEMMs ----------------

// A(bf16) = (x @ W0) * r_out.  64 nodes/block, thread = 4m x 4n, K=128 in two halves.
__global__ __launch_bounds__(256) void k_gemm0(const float* __restrict__ x,
                                               const float* __restrict__ W0,
                                               const float* __restrict__ r_out,
                                               unsigned short* __restrict__ A) {
    __shared__ float xl[64 * 129];
    __shared__ float wl[64 * 64];
    int tid = threadIdx.x;
    int m0 = blockIdx.x * 64;
#pragma unroll
    for (int i = 0; i < 8; ++i) {
        int idx = i * 256 + tid;
        int m = idx >> 5, kc = idx & 31;
        int gm = min(m0 + m, NN - 1);
        float4 v = *(const float4*)&x[(size_t)gm * 128 + kc * 4];
        float* p = &xl[m * 129 + kc * 4];
        p[0] = v.x; p[1] = v.y; p[2] = v.z; p[3] = v.w;
    }
    int tn = tid & 15, tm = tid >> 4;
    float acc[4][4] = {};
    const float4* W4 = (const float4*)W0;
    float4* wl4 = (float4*)wl;
    for (int h = 0; h < 2; ++h) {
        __syncthreads();
#pragma unroll
        for (int i = 0; i < 4; ++i) wl4[i * 256 + tid] = W4[h * 1024 + i * 256 + tid];
        __syncthreads();
#pragma unroll 4
        for (int k = 0; k < 64; ++k) {
            int kk = h * 64 + k;
            float4 wv = *(const float4*)&wl[k * 64 + tn * 4];
            float xv[4];
#pragma unroll
            for (int i = 0; i < 4; ++i) xv[i] = xl[(tm * 4 + i) * 129 + kk];
#pragma unroll
            for (int i = 0; i < 4; ++i) {
                acc[i][0] = fmaf(xv[i], wv.x, acc[i][0]);
                acc[i][1] = fmaf(xv[i], wv.y, acc[i][1]);
                acc[i][2] = fmaf(xv[i], wv.z, acc[i][2]);
                acc[i][3] = fmaf(xv[i], wv.w, acc[i][3]);
            }
        }
    }
#pragma unroll
    for (int i = 0; i < 4; ++i) {
        int m = m0 + tm * 4 + i;
        if (m < NN) {
            float ro = r_out[m];
            US4 o = {f2bf(acc[i][0] * ro), f2bf(acc[i][1] * ro),
                     f2bf(acc[i][2] * ro), f2bf(acc[i][3] * ro)};
            *(US4*)&A[(size_t)m * 64 + tn * 4] = o;
        }
    }
}

// C16(bf16) = ((relu(G @ W1 + b1) @ W2) * r_out).  G is bf16.  64 nodes/block.
__global__ __launch_bounds__(256) void k_mlp(const unsigned short* __restrict__ G,
                                             const float* __restrict__ W1,
                                             const float* __restrict__ b1,
                                             const float* __restrict__ W2,
                                             const float* __restrict__ r_out,
                                             unsigned short* __restrict__ C16) {
    __shared__ float gl[64 * 65];
    __shared__ float w1l[64 * 64];
    __shared__ float w2l[64 * 16];
    int tid = threadIdx.x;
    int m0 = blockIdx.x * 64;
#pragma unroll
    for (int i = 0; i < 2; ++i) {
        int idx = i * 256 + tid;  // 512 chunks of 8 bf16
        int m = idx >> 3, c8 = idx & 7;
        int gm = min(m0 + m, NN - 1);
        uint4 u = *(const uint4*)&G[(size_t)gm * 64 + c8 * 8];
        float* p = &gl[m * 65 + c8 * 8];
        p[0] = bfu(u.x & 0xffffu); p[1] = bfu(u.x >> 16);
        p[2] = bfu(u.y & 0xffffu); p[3] = bfu(u.y >> 16);
        p[4] = bfu(u.z & 0xffffu); p[5] = bfu(u.z >> 16);
        p[6] = bfu(u.w & 0xffffu); p[7] = bfu(u.w >> 16);
    }
    float4* w1l4 = (float4*)w1l;
    const float4* W1_4 = (const float4*)W1;
#pragma unroll
    for (int i = 0; i < 4; ++i) w1l4[i * 256 + tid] = W1_4[i * 256 + tid];
    ((float4*)w2l)[tid] = ((const float4*)W2)[tid];
    __syncthreads();
    int tn = tid & 15, tm = tid >> 4;
    float acc[4][4] = {};
#pragma unroll 4
    for (int k = 0; k < 64; ++k) {
        float4 wv = *(const float4*)&w1l[k * 64 + tn * 4];
        float xv[4];
#pragma unroll
        for (int i = 0; i < 4; ++i) xv[i] = gl[(tm * 4 + i) * 65 + k];
#pragma unroll
        for (int i = 0; i < 4; ++i) {
            acc[i][0] = fmaf(xv[i], wv.x, acc[i][0]);
            acc[i][1] = fmaf(xv[i], wv.y, acc[i][1]);
            acc[i][2] = fmaf(xv[i], wv.z, acc[i][2]);
            acc[i][3] = fmaf(xv[i], wv.w, acc[i][3]);
        }
    }
    float4 bb = *(const float4*)&b1[tn * 4];
    __syncthreads();
#pragma unroll
    for (int i = 0; i < 4; ++i) {
        gl[(tm * 4 + i) * 65 + tn * 4 + 0] = fmaxf(acc[i][0] + bb.x, 0.f);
        gl[(tm * 4 + i) * 65 + tn * 4 + 1] = fmaxf(acc[i][1] + bb.y, 0.f);
        gl[(tm * 4 + i) * 65 + tn * 4 + 2] = fmaxf(acc[i][2] + bb.z, 0.f);
        gl[(tm * 4 + i) * 65 + tn * 4 + 3] = fmaxf(acc[i][3] + bb.w, 0.f);
    }
    __syncthreads();
    int m = tid >> 2, n0 = (tid & 3) * 4;
    float a2[4] = {};
#pragma unroll 8
    for (int k = 0; k < 64; ++k) {
        float zv = gl[m * 65 + k];
        float4 wv = *(const float4*)&w2l[k * 16 + n0];
        a2[0] = fmaf(zv, wv.x, a2[0]);
        a2[1] = fmaf(zv, wv.y, a2[1]);
        a2[2] = fmaf(zv, wv.z, a2[2]);
        a2[3] = fmaf(zv, wv.w, a2[3]);
    }
    int node = m0 + m;
    if (node < NN) {
        float ro = r_out[node];
        US4 o = {f2bf(a2[0] * ro), f2bf(a2[1] * ro), f2bf(a2[2] * ro), f2bf(a2[3] * ro)};
        *(US4*)&C16[(size_t)node * 16 + n0] = o;
    }
}

// ---------------- gathers (register-accumulate, 2 nodes per wave) ----------------

// d=64 bf16 gather, 2 consecutive nodes/wave in lockstep.  8 lanes/edge x uint4;
// per loop body: 2 steps x 2 nodes = 4 independent h-loads + 4 csr loads in
// flight.  All slots dummy-clamped (index NN -> zero row): uniform, no tails.
// MODE 0: o16 = bf16(relu(agg*r_in + bias)*r_out)   (layer0 -> B)
// MODE 1: o16 = bf16(agg*r_in)                      (layer1 -> G, feeds k_mlp)
template <int MODE>
__global__ __launch_bounds__(256) void k_gb64(const int* __restrict__ rowdesc,
                                              const int* __restrict__ csr,
                                              const unsigned short* __restrict__ h,
                                              const float* __restrict__ r_in,
                                              const float* __restrict__ r_out,
                                              const float* __restrict__ bias,
                                              unsigned short* __restrict__ o16) {
    int tid = threadIdx.x;
    int wave = tid >> 6, lane = tid & 63;
    int n0 = (blockIdx.x * 4 + wave) * 2, n1 = n0 + 1;
    int rdA = rowdesc[n0], rdB = rowdesc[n1];
    int jbA = rdA >> 9, degA = rdA & 511;
    int jbB = rdB >> 9, degB = rdB & 511;
    int itn = max((degA + 7) >> 3, (degB + 7) >> 3);
    int g = lane >> 3, f8 = lane & 7;  // g: edge slot in step [0,8), f8: feature octet
    const int* cA = csr + jbA + g;
    const int* cB = csr + jbB + g;
    const unsigned short* hp = h + f8 * 8;
    float aA[8] = {}, aB[8] = {};
    for (int it = 0; it < itn; it += 2) {
        int s0 = it * 8 + g, s1 = s0 + 8;
        int eA0 = cA[it * 8];
        int eA1 = cA[it * 8 + 8];
        int eB0 = cB[it * 8];
        int eB1 = cB[it * 8 + 8];
        eA0 = (s0 < degA) ? eA0 : NN;
        eA1 = (s1 < degA) ? eA1 : NN;
        eB0 = (s0 < degB) ? eB0 : NN;
        eB1 = (s1 < degB) ? eB1 : NN;
        uint4 u0 = *(const uint4*)(hp + (size_t)eA0 * 64);
        uint4 u1 = *(const uint4*)(hp + (size_t)eA1 * 64);
        uint4 u2 = *(const uint4*)(hp + (size_t)eB0 * 64);
        uint4 u3 = *(const uint4*)(hp + (size_t)eB1 * 64);
        aA[0] += bfu(u0.x & 0xffffu); aA[1] += bfu(u0.x >> 16);
        aA[2] += bfu(u0.y & 0xffffu); aA[3] += bfu(u0.y >> 16);
        aA[4] += bfu(u0.z & 0xffffu); aA[5] += bfu(u0.z >> 16);
        aA[6] += bfu(u0.w & 0xffffu); aA[7] += bfu(u0.w >> 16);
        aA[0] += bfu(u1.x & 0xffffu); aA[1] += bfu(u1.x >> 16);
        aA[2] += bfu(u1.y & 0xffffu); aA[3] += bfu(u1.y >> 16);
        aA[4] += bfu(u1.z & 0xffffu); aA[5] += bfu(u1.z >> 16);
        aA[6] += bfu(u1.w & 0xffffu); aA[7] += bfu(u1.w >> 16);
        aB[0] += bfu(u2.x & 0xffffu); aB[1] += bfu(u2.x >> 16);
        aB[2] += bfu(u2.y & 0xffffu); aB[3] += bfu(u2.y >> 16);
        aB[4] += bfu(u2.z & 0xffffu); aB[5] += bfu(u2.z >> 16);
        aB[6] += bfu(u2.w & 0xffffu); aB[7] += bfu(u2.w >> 16);
        aB[0] += bfu(u3.x & 0xffffu); aB[1] += bfu(u3.x >> 16);
        aB[2] += bfu(u3.y & 0xffffu); aB[3] += bfu(u3.y >> 16);
        aB[4] += bfu(u3.z & 0xffffu); aB[5] += bfu(u3.z >> 16);
        aB[6] += bfu(u3.w & 0xffffu); aB[7] += bfu(u3.w >> 16);
    }
#pragma unroll
    for (int m = 8; m <= 32; m <<= 1) {
#pragma unroll
        for (int k = 0; k < 8; ++k) {
            aA[k] += __shfl_xor(aA[k], m);
            aB[k] += __shfl_xor(aB[k], m);
        }
    }
    if (g < 2) {
        int nw = g ? n1 : n0;
        float o[8];
#pragma unroll
        for (int k = 0; k < 8; ++k) o[k] = g ? aB[k] : aA[k];
        float ri = r_in[nw];
        unsigned short ov[8];
        if (MODE == 0) {
            float ro = r_out[nw];
            float4 bA = *(const float4*)&bias[f8 * 8];
            float4 bB = *(const float4*)&bias[f8 * 8 + 4];
            float bb[8] = {bA.x, bA.y, bA.z, bA.w, bB.x, bB.y, bB.z, bB.w};
#pragma unroll
            for (int k = 0; k < 8; ++k)
                ov[k] = f2bf(fmaxf(fmaf(o[k], ri, bb[k]), 0.f) * ro);
        } else {
#pragma unroll
            for (int k = 0; k < 8; ++k) ov[k] = f2bf(o[k] * ri);
        }
        uint4 ow;
        ow.x = (unsigned)ov[0] | ((unsigned)ov[1] << 16);
        ow.y = (unsigned)ov[2] | ((unsigned)ov[3] << 16);
        ow.z = (unsigned)ov[4] | ((unsigned)ov[5] << 16);
        ow.w = (unsigned)ov[6] | ((unsigned)ov[7] << 16);
        *(uint4*)&o16[(size_t)nw * 64 + f8 * 8] = ow;
    }
}

// d=16 bf16 gather: 2 nodes/wave, 8 lanes/edge x uint (2 feats), same structure.
// out = agg*r_in + b2 (fp32 output)
__global__ __launch_bounds__(256) void k_gb16(const int* __restrict__ rowdesc,
                                              const int* __restrict__ csr,
                                              const unsigned short* __restrict__ C16,
                                              const float* __restrict__ r_in,
                                              const float* __restrict__ b2,
                                              float* __restrict__ out) {
    int tid = threadIdx.x;
    int wave = tid >> 6, lane = tid & 63;
    int n0 = (blockIdx.x * 4 + wave) * 2, n1 = n0 + 1;
    int rdA = rowdesc[n0], rdB = rowdesc[n1];
    int jbA = rdA >> 9, degA = rdA & 511;
    int jbB = rdB >> 9, degB = rdB & 511;
    int itn = max((degA + 7) >> 3, (degB + 7) >> 3);
    int g = lane >> 3, p = lane & 7;  // p: feature pair [0,8)
    const int* cA = csr + jbA + g;
    const int* cB = csr + jbB + g;
    const unsigned short* cp = C16 + p * 2;
    float a0A = 0.f, a1A = 0.f, a0B = 0.f, a1B = 0.f;
    for (int it = 0; it < itn; it += 2) {
        int s0 = it * 8 + g, s1 = s0 + 8;
        int eA0 = cA[it * 8];
        int eA1 = cA[it * 8 + 8];
        int eB0 = cB[it * 8];
        int eB1 = cB[it * 8 + 8];
        eA0 = (s0 < degA) ? eA0 : NN;
        eA1 = (s1 < degA) ? eA1 : NN;
        eB0 = (s0 < degB) ? eB0 : NN;
        eB1 = (s1 < degB) ? eB1 : NN;
        unsigned u0 = *(const unsigned*)(cp + (size_t)eA0 * 16);
        unsigned u1 = *(const unsigned*)(cp + (size_t)eA1 * 16);
        unsigned u2 = *(const unsigned*)(cp + (size_t)eB0 * 16);
        unsigned u3 = *(const unsigned*)(cp + (size_t)eB1 * 16);
        a0A += bfu(u0 & 0xffffu); a1A += bfu(u0 >> 16);
        a0A += bfu(u1 & 0xffffu); a1A += bfu(u1 >> 16);
        a0B += bfu(u2 & 0xffffu); a1B += bfu(u2 >> 16);
        a0B += bfu(u3 & 0xffffu); a1B += bfu(u3 >> 16);
    }
#pragma unroll
    for (int m = 8; m <= 32; m <<= 1) {
        a0A += __shfl_xor(a0A, m);
        a1A += __shfl_xor(a1A, m);
        a0B += __shfl_xor(a0B, m);
        a1B += __shfl_xor(a1B, m);
    }
    if (g < 2) {
        int nw = g ? n1 : n0;
        float x0 = g ? a0B : a0A;
        float x1 = g ? a1B : a1A;
        float ri = r_in[nw];
        float2 bb = *(const float2*)&b2[p * 2];
        float2 o;
        o.x = fmaf(x0, ri, bb.x);
        o.y = fmaf(x1, ri, bb.y);
        *(float2*)&out[(size_t)nw * 16 + p * 2] = o;
    }
}

extern "C" void kernel_launch(void* const* d_in, const int* in_sizes, int n_in,
                              void* d_out, int out_size, void* d_ws, size_t ws_size,
                              hipStream_t stream) {
    const float* feats = (const float*)d_in[0];
    const int* src = (const int*)d_in[1];
    const int* dst = (const int*)d_in[2];
    const float* W0 = (const float*)d_in[3];
    const float* b0 = (const float*)d_in[4];
    const float* W1 = (const float*)d_in[5];
    const float* b1 = (const float*)d_in[6];
    const float* W2 = (const float*)d_in[7];
    const float* b2 = (const float*)d_in[8];
    float* out = (float*)d_out;

    // ws (4B units):
    //   r_out[NN] | r_in[NN] | rowdesc[NN] | EB[NE+16] (E2d then csr in-place, +guard) |
    //   E2s[NE bytes = NE/4] | R1[32(NN+1)] (A bf16 then G bf16) | R2[32(NN+1)] (B bf16) |
    //   C16[8(NN+1)] | base_d[NBUCK+1] cursor_d[NBUCK] base_s[NBUCK+1] cursor_s[NBUCK] |
    //   bcnt8_d[8*NBUCK] bcnt8_s[8*NBUCK]
    float* ws = (float*)d_ws;
    float* r_out = ws;
    float* r_in = ws + NN;
    int* rowdesc = (int*)(ws + 2 * NN);
    int* EB = (int*)(ws + 3 * NN);  // NE + 16
    unsigned char* E2s = (unsigned char*)(ws + 3 * NN + NE + 16);
    float* R1 = ws + 3 * NN + NE + 16 + NE / 4;
    float* R2 = R1 + (size_t)32 * (NN + 1);
    float* Creg = R2 + (size_t)32 * (NN + 1);
    int* base_d = (int*)(Creg + (size_t)8 * (NN + 1));
    int* cursor_d = base_d + NBUCK + 1;
    int* base_s = cursor_d + NBUCK;
    int* cursor_s = base_s + NBUCK + 1;
    int* bcnt8_d = cursor_s + NBUCK;
    int* bcnt8_s = bcnt8_d + NREP * NBUCK;

    unsigned short* A = (unsigned short*)R1;
    unsigned short* G = A;  // after k_gb64<0> consumes A, region reused for G
    unsigned short* B = (unsigned short*)R2;
    unsigned short* C16 = (unsigned short*)Creg;

    // build (CSR in place over the bucket-ordered edge array)
    hipMemsetAsync(bcnt8_d, 0, 2 * NREP * NBUCK * sizeof(int), stream);
    k_hist<<<HISTB, 256, 0, stream>>>(src, dst, bcnt8_d, bcnt8_s);
    k_bscan<<<3, 1024, 0, stream>>>(bcnt8_d, bcnt8_s, base_d, cursor_d, base_s, cursor_s,
                                    A, B, C16, EB);
    k_pairs<<<(NE + PCHUNK - 1) / PCHUNK, 256, 0, stream>>>(src, dst, cursor_d, cursor_s,
                                                            EB, E2s);
    k_nodes<<<2 * NBUCK, 256, 0, stream>>>(EB, base_d, E2s, base_s, rowdesc, r_in, r_out);

    // layer 0
    k_gemm0<<<(NN + 63) / 64, 256, 0, stream>>>(feats, W0, r_out, A);
    k_gb64<0><<<NN / 8, 256, 0, stream>>>(rowdesc, EB, A, r_in, r_out, b0, B);

    // layer 1 (+ layer2 pre-GEMM)
    k_gb64<1><<<NN / 8, 256, 0, stream>>>(rowdesc, EB, B, r_in, r_out, b0, G);
    k_mlp<<<(NN + 63) / 64, 256, 0, stream>>>(G, W1, b1, W2, r_out, C16);

    // layer 2
    k_gb16<<<NN / 8, 256, 0, stream>>>(rowdesc, EB, C16, r_in, b2, out);
}